// Round 1
// baseline (211.852 us; speedup 1.0000x reference)
//
#include <hip/hip_runtime.h>

#define NEG_INF (-9999999.0f)

typedef __attribute__((ext_vector_type(8))) short bf16x8;
typedef __attribute__((ext_vector_type(4))) float f32x4;
typedef unsigned short us;
typedef unsigned int u32;

#define MFMA16 __builtin_amdgcn_mfma_f32_16x16x32_bf16

__device__ __forceinline__ float b2f(us u) {
  union { unsigned int i; float f; } x; x.i = ((unsigned int)u) << 16; return x.f;
}
__device__ __forceinline__ us f2b(float f) {
  union { float f; unsigned int i; } x; x.f = f;
  unsigned int r = x.i + 0x7fffu + ((x.i >> 16) & 1u);
  return (us)(r >> 16);
}
__device__ __forceinline__ float lrelu(float v) { return v > 0.f ? v : 0.01f * v; }
__device__ __forceinline__ bf16x8 ld8(const us* p) { return *reinterpret_cast<const bf16x8*>(p); }
// XOR swizzle for the 64x320 bf16 LDS panels (row pitch 640B -> all rows same bank
// without it). Spreads 16B chunks of 8 consecutive rows across 8 bank groups.
__device__ __forceinline__ int swz(int row) { return (row & 7) << 4; }

// ---------------- prep: weights -> bf16 [320][320] panels, c2 = Wr2 @ root ----------------
__global__ __launch_bounds__(256) void k_prep(
    const float* __restrict__ Ws, const float* __restrict__ Wp, const float* __restrict__ Wc,
    const float* __restrict__ Wr, const float* __restrict__ root,
    us* __restrict__ Wsb, us* __restrict__ Wpb, us* __restrict__ Wcb,
    us* __restrict__ Wr3b, float* __restrict__ c2) {
  int task = blockIdx.y;
  int gid = blockIdx.x * 256 + threadIdx.x;
  const int stride = 80 * 256;
  if (task < 3) {
    const float* src = (task == 0) ? Ws : (task == 1) ? Wp : Wc;
    us* dst = (task == 0) ? Wsb : (task == 1) ? Wpb : Wcb;
    for (int i = gid; i < 320 * 320; i += stride) {
      int r = i / 320, c = i - r * 320;
      dst[i] = (r < 300 && c < 300) ? f2b(src[r * 300 + c]) : (us)0;
    }
  } else if (task == 3) {
    // Wr [300][900] -> three [320][320] panels (seg 0/1/2 = enc/agg/tmp3 slices)
    for (int i = gid; i < 3 * 320 * 320; i += stride) {
      int seg = i / 102400, rem = i - seg * 102400;
      int r = rem / 320, c = rem - r * 320;
      Wr3b[i] = (r < 300 && c < 300) ? f2b(Wr[r * 900 + seg * 300 + c]) : (us)0;
    }
  } else {
    // c2[c] = sum_h Wr2[c][h] * root[h], padded to 320
    for (int i = gid; i < 320 * 8; i += stride) {
      int c = i >> 3, p = i & 7;
      float s = 0.f;
      if (c < 300)
        for (int h = p; h < 300; h += 8) s = fmaf(Wr[c * 900 + 300 + h], root[h], s);
      s += __shfl_xor(s, 1); s += __shfl_xor(s, 2); s += __shfl_xor(s, 4);
      if (p == 0) c2[c] = s;
    }
  }
}

// ---------------- core sweep: A = 2 row-tiles from swizzled LDS, B = global [320][320] ----
template<int NT, int KS>
__device__ __forceinline__ void sweep2(const us* __restrict__ Alds, int r0, int r1, int q, int lo,
    const us* __restrict__ Bg, int n0, f32x4 (&acc)[2][NT]) {
  const char* ab = (const char*)Alds;
  const int a0o = r0 * 640, s0 = swz(r0);
  const int a1o = r1 * 640, s1 = swz(r1);
  const us* br[NT];
#pragma unroll
  for (int t = 0; t < NT; ++t)
    br[t] = Bg + (long)((n0 + t) * 16 + lo) * 320 + 8 * q;
  bf16x8 aC[2], aN[2], b0[NT], b1[NT];
  aC[0] = *(const bf16x8*)(ab + a0o + ((16 * q) ^ s0));
  aC[1] = *(const bf16x8*)(ab + a1o + ((16 * q) ^ s1));
  aN[0] = *(const bf16x8*)(ab + a0o + ((64 + 16 * q) ^ s0));
  aN[1] = *(const bf16x8*)(ab + a1o + ((64 + 16 * q) ^ s1));
#pragma unroll
  for (int t = 0; t < NT; ++t) b0[t] = ld8(br[t]);
#pragma unroll
  for (int t = 0; t < NT; ++t) b1[t] = ld8(br[t] + 32);
#pragma unroll
  for (int ks = 0; ks < KS - 2; ++ks) {
    bf16x8 aF[2], bF[NT];
    const int kb = 64 * (ks + 2) + 16 * q;
    aF[0] = *(const bf16x8*)(ab + a0o + (kb ^ s0));
    aF[1] = *(const bf16x8*)(ab + a1o + (kb ^ s1));
#pragma unroll
    for (int t = 0; t < NT; ++t) bF[t] = ld8(br[t] + (ks + 2) * 32);
#pragma unroll
    for (int t = 0; t < NT; ++t) {
      acc[0][t] = MFMA16(aC[0], b0[t], acc[0][t], 0, 0, 0);
      acc[1][t] = MFMA16(aC[1], b0[t], acc[1][t], 0, 0, 0);
    }
    aC[0] = aN[0]; aC[1] = aN[1]; aN[0] = aF[0]; aN[1] = aF[1];
#pragma unroll
    for (int t = 0; t < NT; ++t) { b0[t] = b1[t]; b1[t] = bF[t]; }
  }
#pragma unroll
  for (int t = 0; t < NT; ++t) {
    acc[0][t] = MFMA16(aC[0], b0[t], acc[0][t], 0, 0, 0);
    acc[1][t] = MFMA16(aC[1], b0[t], acc[1][t], 0, 0, 0);
  }
#pragma unroll
  for (int t = 0; t < NT; ++t) {
    acc[0][t] = MFMA16(aN[0], b1[t], acc[0][t], 0, 0, 0);
    acc[1][t] = MFMA16(aN[1], b1[t], acc[1][t], 0, 0, 0);
  }
}

// epilogue: acc -> lrelu(+bias) -> bf16 into swizzled 64x320 LDS panel (cols <300 only;
// pad columns stay zero from the phase-0 clear)
__device__ __forceinline__ void epi_lds(const f32x4 (&acc)[2][5], const float* __restrict__ bias,
    us* __restrict__ dst, int mh, int nq, int lo, int q) {
#pragma unroll
  for (int mi = 0; mi < 2; ++mi)
#pragma unroll
    for (int tt = 0; tt < 5; ++tt) {
      int col = (nq * 5 + tt) * 16 + lo;
      if (col < 300) {
        float bb = bias[col];
#pragma unroll
        for (int r = 0; r < 4; ++r) {
          int row = (mh * 2 + mi) * 16 + 4 * q + r;
          *(us*)((char*)dst + row * 640 + ((2 * col) ^ swz(row))) =
              f2b(lrelu(acc[mi][tt][r] + bb));
        }
      }
    }
}

// ---------------- mega: one block per document, everything in LDS ----------------
__global__ __launch_bounds__(512, 2) void k_mega(
    const int* __restrict__ wi, const float* __restrict__ E,
    const us* __restrict__ Wsb, const us* __restrict__ Wpb, const us* __restrict__ Wcb,
    const us* __restrict__ Wrb, const float* __restrict__ c2,
    const float* __restrict__ b_sent, const float* __restrict__ b_par,
    const float* __restrict__ b_ch,
    const float* __restrict__ w_root, const float* __restrict__ b_root,
    const float* __restrict__ b_r, const float* __restrict__ W_cls,
    const float* __restrict__ b_cls,
    float* __restrict__ outp, float* __restrict__ outA, float* __restrict__ outF) {
  __shared__ __align__(16) us BIG[61440];        // 3 x [64][320] bf16 panels (122880 B)
  __shared__ __align__(16) float LA[64 * 68];    // logits / A fp32 (17408 B)
  __shared__ __align__(16) us AtL[64 * 72];      // A^T bf16, pitch 72 (9216 B)
  __shared__ float pm[512], ps[512];             // softmax partials (4096 B)
  __shared__ float scS[64], friS[64], rsS[64];
  __shared__ float finP[640];                    // per-m-half column sums (2560 B)

  const int d = blockIdx.x, t = threadIdx.x;
  const int w = t >> 6, lane = t & 63, lo = lane & 15, q = lane >> 4;
  const int mh = w & 1, nq = w >> 1;             // m-half x n-quarter wave decomposition
  const int r0 = mh * 32 + lo, r1 = r0 + 16;
  const f32x4 z4 = {0.f, 0.f, 0.f, 0.f};
  us* const Pl = BIG + 20480;
  us* const Cl = BIG + 40960;
  us* const G2T = BIG + 20480;                   // [320][72] bf16, reuses P(+C) space

  // phase 0: clear panels (pad columns must be zero)
  {
    u32* zb = (u32*)BIG;
#pragma unroll
    for (int i = 0; i < 60; ++i) zb[t + i * 512] = 0u;
  }
  __syncthreads();

  // phase 1: gather x_last = E[wi[d, s, 63]] -> panel 0 (swizzled bf16)
  {
    int s = t >> 3, p = t & 7;
    int widx = wi[((d * 64 + s) << 6) + 63];
    const float4* er = (const float4*)(E + (long)widx * 300);
    char* rowb = (char*)BIG + s * 640;
    int sw = swz(s);
    for (int j = p; j < 75; j += 8) {
      float4 v = er[j];
      ushort4 h4 = make_ushort4(f2b(v.x), f2b(v.y), f2b(v.z), f2b(v.w));
      *(ushort4*)(rowb + ((8 * j) ^ sw)) = h4;
    }
  }
  __syncthreads();

  // phase 2: enc = lrelu(x @ Ws^T + b), written IN PLACE over x
  {
    f32x4 acc[2][5];
#pragma unroll
    for (int a = 0; a < 2; ++a)
#pragma unroll
      for (int b = 0; b < 5; ++b) acc[a][b] = z4;
    sweep2<5, 10>(BIG, r0, r1, q, lo, Wsb, nq * 5, acc);
    __syncthreads();               // all reads of x done before overwrite
    epi_lds(acc, b_sent, BIG, mh, nq, lo, q);
  }
  __syncthreads();

  // phase 2b: scores = enc @ w_root + b_root; fri = softmax(scores)
  {
    int i = t >> 3, p = t & 7;
    float s = 0.f;
    for (int cch = p; cch < 38; cch += 8) {
      bf16x8 v = *(const bf16x8*)((const char*)BIG + i * 640 + ((16 * cch) ^ swz(i)));
#pragma unroll
      for (int e = 0; e < 8; ++e) {
        int h = cch * 8 + e;
        if (h < 300) s = fmaf(b2f((us)v[e]), w_root[h], s);
      }
    }
    s += __shfl_xor(s, 1); s += __shfl_xor(s, 2); s += __shfl_xor(s, 4);
    if (p == 0) scS[i] = s + b_root[0];
  }
  __syncthreads();
  if (t < 64) {
    float sc = scS[t], m = sc;
#pragma unroll
    for (int o = 32; o > 0; o >>= 1) m = fmaxf(m, __shfl_xor(m, o));
    float e = expf(sc - m), sum = e;
#pragma unroll
    for (int o = 32; o > 0; o >>= 1) sum += __shfl_xor(sum, o);
    float f = e / sum;
    friS[t] = f;
    outF[d * 64 + t] = f;
  }

  // phase 3: P = lrelu(enc @ Wp^T + b), C = lrelu(enc @ Wc^T + b)
  {
    f32x4 acc[2][5];
#pragma unroll
    for (int a = 0; a < 2; ++a)
#pragma unroll
      for (int b = 0; b < 5; ++b) acc[a][b] = z4;
    sweep2<5, 10>(BIG, r0, r1, q, lo, Wpb, nq * 5, acc);
    epi_lds(acc, b_par, Pl, mh, nq, lo, q);
  }
  {
    f32x4 acc[2][5];
#pragma unroll
    for (int a = 0; a < 2; ++a)
#pragma unroll
      for (int b = 0; b < 5; ++b) acc[a][b] = z4;
    sweep2<5, 10>(BIG, r0, r1, q, lo, Wcb, nq * 5, acc);
    epi_lds(acc, b_ch, Cl, mh, nq, lo, q);
  }
  __syncthreads();

  // phase 4: logits L = P @ C^T (64x64, K=320), diag masked
  {
    int m = w >> 1, np = (w & 1) * 2;
    int arow = m * 16 + lo;
    int brow0 = np * 16 + lo, brow1 = brow0 + 16;
    int sa = swz(arow), sb0 = swz(brow0), sb1 = swz(brow1);
    f32x4 a0 = z4, a1 = z4;
#pragma unroll
    for (int ks = 0; ks < 10; ++ks) {
      int kb = 64 * ks + 16 * q;
      bf16x8 av  = *(const bf16x8*)((const char*)Pl + arow * 640 + (kb ^ sa));
      bf16x8 bv0 = *(const bf16x8*)((const char*)Cl + brow0 * 640 + (kb ^ sb0));
      bf16x8 bv1 = *(const bf16x8*)((const char*)Cl + brow1 * 640 + (kb ^ sb1));
      a0 = MFMA16(av, bv0, a0, 0, 0, 0);
      a1 = MFMA16(av, bv1, a1, 0, 0, 0);
    }
#pragma unroll
    for (int r = 0; r < 4; ++r) {
      int row = m * 16 + 4 * q + r;
      int c0 = np * 16 + lo, c1 = c0 + 16;
      LA[row * 68 + c0] = (row == c0) ? NEG_INF : a0[r];
      LA[row * 68 + c1] = (row == c1) ? NEG_INF : a1[r];
    }
  }
  __syncthreads();

  // phase 4b: column softmax (axis=1 over i); write A (fp32 global), A^T (bf16 LDS), rs
  {
    int j = lane, p2 = w;
    float mx = -3.0e38f;
#pragma unroll
    for (int ii = 0; ii < 8; ++ii) mx = fmaxf(mx, LA[(p2 * 8 + ii) * 68 + j]);
    pm[p2 * 64 + j] = mx;
    __syncthreads();
    float gm = pm[j];
#pragma unroll
    for (int k = 1; k < 8; ++k) gm = fmaxf(gm, pm[k * 64 + j]);
    float ev[8], s = 0.f;
#pragma unroll
    for (int ii = 0; ii < 8; ++ii) {
      float e = expf(LA[(p2 * 8 + ii) * 68 + j] - gm);
      ev[ii] = e; s += e;
    }
    ps[p2 * 64 + j] = s;
    __syncthreads();
    float tot = ps[j];
#pragma unroll
    for (int k = 1; k < 8; ++k) tot += ps[k * 64 + j];
    float inv = 1.f / tot;
    float* Ad = outA + (long)d * 4096;
#pragma unroll
    for (int ii = 0; ii < 8; ++ii) {
      int i = p2 * 8 + ii;
      float a = ev[ii] * inv;
      Ad[i * 64 + j] = a;
      AtL[j * 72 + i] = f2b(a);
      LA[i * 68 + j] = a;
    }
  }
  __syncthreads();
  if (t < 64) {   // rs[i] = sum_j A[i][j]
    float s = 0.f;
    for (int jj = 0; jj < 64; ++jj) s += LA[t * 68 + jj];
    rsS[t] = s;
  }

  // phase 5: G2e = enc @ Wr2^T, stored TRANSPOSED ([col][row]) over dead P/C space
  {
    f32x4 acc[2][5];
#pragma unroll
    for (int a = 0; a < 2; ++a)
#pragma unroll
      for (int b = 0; b < 5; ++b) acc[a][b] = z4;
    sweep2<5, 10>(BIG, r0, r1, q, lo, Wrb + 102400, nq * 5, acc);
#pragma unroll
    for (int mi = 0; mi < 2; ++mi)
#pragma unroll
      for (int tt = 0; tt < 5; ++tt) {
        int col = (nq * 5 + tt) * 16 + lo;
        if (col < 300) {
#pragma unroll
          for (int r = 0; r < 4; ++r) {
            int row = (mh * 2 + mi) * 16 + 4 * q + r;
            G2T[col * 72 + row] = f2b(acc[mi][tt][r]);
          }
        }
      }
    // zero pad rows 300..319 of G2T (stale P/C bytes otherwise)
    for (int i2 = t; i2 < 720; i2 += 512) ((u32*)(G2T + 21600))[i2] = 0u;
  }
  __syncthreads();

  // phase 6: ri = lrelu(enc@Wr1^T + A^T@G2e + rs*(enc@Wr3^T) + fri*c2 + b_r),
  //          reduced over sentences into finP (never materialized)
  {
    f32x4 am[2][5], ag[2][5];
#pragma unroll
    for (int a = 0; a < 2; ++a)
#pragma unroll
      for (int b = 0; b < 5; ++b) { am[a][b] = z4; ag[a][b] = z4; }
    sweep2<5, 10>(BIG, r0, r1, q, lo, Wrb, nq * 5, am);           // G1 (enc seg)
    sweep2<5, 10>(BIG, r0, r1, q, lo, Wrb + 204800, nq * 5, ag);  // G3 (tmp3 seg)
    // G2r: A^T @ G2e  (K = 64, both operands in LDS)
#pragma unroll
    for (int ks = 0; ks < 2; ++ks) {
      bf16x8 aA = *(const bf16x8*)(AtL + r0 * 72 + 32 * ks + 8 * q);
      bf16x8 aB = *(const bf16x8*)(AtL + r1 * 72 + 32 * ks + 8 * q);
#pragma unroll
      for (int tt = 0; tt < 5; ++tt) {
        bf16x8 bv = *(const bf16x8*)(G2T + ((nq * 5 + tt) * 16 + lo) * 72 + 32 * ks + 8 * q);
        am[0][tt] = MFMA16(aA, bv, am[0][tt], 0, 0, 0);
        am[1][tt] = MFMA16(aB, bv, am[1][tt], 0, 0, 0);
      }
    }
#pragma unroll
    for (int tt = 0; tt < 5; ++tt) {
      int col = (nq * 5 + tt) * 16 + lo;
      float bb = (col < 300) ? b_r[col] : 0.f;
      float cc = c2[col];
      float csum = 0.f;
#pragma unroll
      for (int mi = 0; mi < 2; ++mi)
#pragma unroll
        for (int r = 0; r < 4; ++r) {
          int i = (mh * 2 + mi) * 16 + 4 * q + r;
          csum += lrelu(am[mi][tt][r] + rsS[i] * ag[mi][tt][r] + friS[i] * cc + bb);
        }
      csum += __shfl_xor(csum, 16);
      csum += __shfl_xor(csum, 32);
      if (q == 0) finP[mh * 320 + col] = csum;   // sum over 32 sentences of this m-half
    }
  }
  __syncthreads();

  // phase 7: out = (mean_i ri) @ W_cls^T + b_cls
  if (t < 128) {
    int cls = t >> 6, ln = t & 63;
    float s = 0.f;
    for (int h = ln; h < 300; h += 64)
      s += (finP[h] + finP[320 + h]) * W_cls[cls * 300 + h];
#pragma unroll
    for (int o = 32; o > 0; o >>= 1) s += __shfl_xor(s, o);
    if (ln == 0) outp[d * 2 + cls] = s * 0.015625f + b_cls[cls];
  }
}

extern "C" void kernel_launch(void* const* d_in, const int* in_sizes, int n_in,
                              void* d_out, int out_size, void* d_ws, size_t ws_size,
                              hipStream_t stream) {
  const int*   wi     = (const int*)d_in[0];
  const float* E      = (const float*)d_in[1];
  const float* W_sent = (const float*)d_in[2];
  const float* b_sent = (const float*)d_in[3];
  const float* W_par  = (const float*)d_in[4];
  const float* b_par  = (const float*)d_in[5];
  const float* W_ch   = (const float*)d_in[6];
  const float* b_ch   = (const float*)d_in[7];
  const float* w_root = (const float*)d_in[8];
  const float* b_root = (const float*)d_in[9];
  const float* root_e = (const float*)d_in[10];
  const float* W_r    = (const float*)d_in[11];
  const float* b_r    = (const float*)d_in[12];
  const float* W_cls  = (const float*)d_in[13];
  const float* b_cls  = (const float*)d_in[14];

  us* B = (us*)d_ws;
  us* Wsb  = B;                     // 102400  [320][320] bf16
  us* Wpb  = B + 102400;
  us* Wcb  = B + 204800;
  us* Wr3b = B + 307200;            // 3 x [320][320] bf16 (seg0/1/2)
  float* c2 = (float*)(B + 614400); // [320] fp32 = Wr2 @ root (padded)

  float* outp = (float*)d_out;      // [out(128) | A(262144) | fri(4096)]
  float* outA = outp + 128;
  float* outF = outp + 128 + 262144;

  k_prep<<<dim3(80, 5), 256, 0, stream>>>(W_sent, W_par, W_ch, W_r, root_e,
                                          Wsb, Wpb, Wcb, Wr3b, c2);
  k_mega<<<64, 512, 0, stream>>>(wi, E, Wsb, Wpb, Wcb, Wr3b, c2,
                                 b_sent, b_par, b_ch, w_root, b_root,
                                 b_r, W_cls, b_cls, outp, outA, outF);
}